// Round 3
// baseline (164.630 us; speedup 1.0000x reference)
//
#include <hip/hip_runtime.h>

// PairwiseLoss: weighted 2-class cross-entropy + top-1 accuracy over all
// probe×gallery pairs.
//   labels[i,j] = (tp[i]==tg[j]); logits[i,j,:] = cls_encode[i,j,0:2]
//   loss = sum(w*nll)/sum(w),  w = label ? 1 : 1/4095
//   prec = 100 * mean(argmax(logits)==label)
//
// R1: libm softplus in predicated ternary = VALU-bound (116 us, VALUBusy 100%).
// R2: __expf/__logf branch-free softplus -> 33 us, memory-bound-ish.
// R3: fuse final reduce (last-block ticket, no 2nd launch), drop LDS staging
//     barrier, issue all 16 loads/thread up-front for max MLP.

constexpr int BATCH = 4096;
constexpr float W_NEG_F = 1.0f / 4095.0f;  // matches fp32 W_NEG in reference

__global__ __launch_bounds__(256) void pl_fused(
    const float* __restrict__ logits,   // [BATCH*BATCH*2]
    const int* __restrict__ tp,         // [BATCH]
    const int* __restrict__ tg,         // [BATCH]
    double* __restrict__ part_wnll,     // [BATCH]
    int* __restrict__ part_pos,         // [BATCH]
    int* __restrict__ part_cor,         // [BATCH]
    unsigned int* __restrict__ counter, // [1], zeroed by memset each call
    float* __restrict__ out)            // out[0]=loss, out[1]=prec
{
    const int t = threadIdx.x;
    const int row = blockIdx.x;

    const int my = tp[row];  // wave-uniform scalar load
    const float4* rowp =
        reinterpret_cast<const float4*>(logits) + (size_t)row * (BATCH / 2);
    const int2* tg2 = reinterpret_cast<const int2*>(tg);

    // Issue the whole row's loads up-front: 8 x float4 (HBM, coalesced 16B/lane)
    // + 8 x int2 (L1/L2-resident 16KB gallery array). No barrier in main path.
    float4 q[8];
    int2 g[8];
#pragma unroll
    for (int k = 0; k < 8; ++k) q[k] = rowp[t + k * 256];
#pragma unroll
    for (int k = 0; k < 8; ++k) g[k] = tg2[t + k * 256];

    float sum_all = 0.f;   // sum of nll over all pairs this thread sees
    float sum_pos = 0.f;   // sum of nll over positive pairs only
    int pos = 0, cor = 0;

#pragma unroll
    for (int k = 0; k < 8; ++k) {
        // pair 0: logits (q.x, q.y), gallery label g.x
        {
            const bool lab = (my == g[k].x);
            const float e = q[k].y - q[k].x;   // d when lab==0
            const float d = lab ? -e : e;      // d = logit_other - logit_true
            // softplus(d) = max(d,0) + log(1+exp(-|d|)); HW v_exp/v_log
            const float nll = fmaxf(d, 0.f) + __logf(1.f + __expf(-fabsf(d)));
            sum_all += nll;
            sum_pos += lab ? nll : 0.f;
            pos += lab ? 1 : 0;
            cor += (((q[k].y > q[k].x)) == lab) ? 1 : 0;  // argmax first-idx ties
        }
        // pair 1: logits (q.z, q.w), gallery label g.y
        {
            const bool lab = (my == g[k].y);
            const float e = q[k].w - q[k].z;
            const float d = lab ? -e : e;
            const float nll = fmaxf(d, 0.f) + __logf(1.f + __expf(-fabsf(d)));
            sum_all += nll;
            sum_pos += lab ? nll : 0.f;
            pos += lab ? 1 : 0;
            cor += (((q[k].w > q[k].z)) == lab) ? 1 : 0;
        }
    }

    // weighted combination, then wave64 shuffle reduce (double for the sum)
    double dw = (double)W_NEG_F * (double)sum_all +
                (1.0 - (double)W_NEG_F) * (double)sum_pos;
#pragma unroll
    for (int off = 32; off > 0; off >>= 1) {
        dw += __shfl_down(dw, off);
        pos += __shfl_down(pos, off);
        cor += __shfl_down(cor, off);
    }
    __shared__ double s_dw[4];
    __shared__ int s_pos[4], s_cor[4];
    __shared__ bool s_last;
    const int wave = t >> 6, lane = t & 63;
    if (lane == 0) { s_dw[wave] = dw; s_pos[wave] = pos; s_cor[wave] = cor; }
    __syncthreads();

    if (t == 0) {
        part_wnll[row] = s_dw[0] + s_dw[1] + s_dw[2] + s_dw[3];
        part_pos[row] = s_pos[0] + s_pos[1] + s_pos[2] + s_pos[3];
        part_cor[row] = s_cor[0] + s_cor[1] + s_cor[2] + s_cor[3];
        __threadfence();  // release partials (device scope)
        const unsigned prev = atomicAdd(counter, 1u);  // device-scope ticket
        s_last = (prev == (unsigned)(gridDim.x - 1));
    }
    __syncthreads();
    if (!s_last) return;

    // ---- last block: fixed-order final reduce (deterministic) ----
    __threadfence();  // acquire: make all blocks' partials visible
    double fdw = 0.0;
    long long fpos = 0, fcor = 0;
    for (int v = t; v < BATCH; v += 256) {
        fdw += part_wnll[v];
        fpos += (long long)part_pos[v];
        fcor += (long long)part_cor[v];
    }
#pragma unroll
    for (int off = 32; off > 0; off >>= 1) {
        fdw += __shfl_down(fdw, off);
        fpos += __shfl_down(fpos, off);
        fcor += __shfl_down(fcor, off);
    }
    __shared__ double f_dw[4];
    __shared__ long long f_pos[4], f_cor[4];
    if (lane == 0) { f_dw[wave] = fdw; f_pos[wave] = fpos; f_cor[wave] = fcor; }
    __syncthreads();
    if (t == 0) {
        const double tot = f_dw[0] + f_dw[1] + f_dw[2] + f_dw[3];
        const long long P = f_pos[0] + f_pos[1] + f_pos[2] + f_pos[3];
        const long long C = f_cor[0] + f_cor[1] + f_cor[2] + f_cor[3];
        const double NP = (double)BATCH * (double)BATCH;
        // sum_w is exact given the positive count
        const double sum_w = (double)P + (NP - (double)P) * (double)W_NEG_F;
        out[0] = (float)(tot / sum_w);
        out[1] = (float)(100.0 * (double)C / NP);
    }
}

extern "C" void kernel_launch(void* const* d_in, const int* in_sizes, int n_in,
                              void* d_out, int out_size, void* d_ws, size_t ws_size,
                              hipStream_t stream) {
    const float* logits = (const float*)d_in[0];  // cls_encode [4096,4096,2] f32
    const int* tp = (const int*)d_in[1];          // tar_probe  [4096] i32
    const int* tg = (const int*)d_in[2];          // tar_gallery[4096] i32
    float* out = (float*)d_out;                   // [loss, prec]

    // workspace: 4096 doubles | 4096 ints | 4096 ints | ticket counter
    double* part_wnll = (double*)d_ws;
    int* part_pos = (int*)((char*)d_ws + BATCH * sizeof(double));
    int* part_cor = part_pos + BATCH;
    unsigned int* counter = (unsigned int*)(part_cor + BATCH);

    // zero the ticket (stream-ordered; becomes a memset node under capture)
    hipMemsetAsync(counter, 0, sizeof(unsigned int), stream);
    pl_fused<<<BATCH, 256, 0, stream>>>(logits, tp, tg, part_wnll, part_pos,
                                        part_cor, counter, out);
}

// Round 4
// 31.749 us; speedup vs baseline: 5.1853x; 5.1853x over previous
//
#include <hip/hip_runtime.h>

// PairwiseLoss: weighted 2-class cross-entropy + top-1 accuracy over all
// probe×gallery pairs.
//   labels[i,j] = (tp[i]==tg[j]); logits[i,j,:] = cls_encode[i,j,0:2]
//   loss = sum(w*nll)/sum(w),  w = label ? 1 : 1/4095
//   prec = 100 * mean(argmax(logits)==label)
//
// R1: libm softplus in predicated ternary -> VALU-bound (116 us, VALUBusy 100%).
// R2: __expf/__logf branch-free softplus -> 33 us, ~80% of streaming ceiling.
// R3 FAILED: fused last-block ticket w/ __threadfence -> 4096 per-block L2
//     writebacks (non-coherent per-XCD L2) -> 250 us, all pipes idle. Reverted.
// R4: two-kernel structure kept; partials inner loop restructured for MLP:
//     4 loads issued before the staging barrier, explicit 2x4-deep pipeline
//     with named registers (no arrays -> no scratch risk).

constexpr int BATCH = 4096;
constexpr float W_NEG_F = 1.0f / 4095.0f;  // matches fp32 W_NEG in reference

__device__ __forceinline__ void pl_pair(float x, float y, bool lab,
                                        float& sum_all, float& sum_pos,
                                        int& pos, int& cor) {
    const float e = y - x;            // d when lab==0
    const float d = lab ? -e : e;     // d = logit_other - logit_true
    // softplus(d) = max(d,0) + log(1+exp(-|d|)); HW v_exp/v_log intrinsics
    const float nll = fmaxf(d, 0.f) + __logf(1.f + __expf(-fabsf(d)));
    sum_all += nll;
    sum_pos += lab ? nll : 0.f;
    pos += lab ? 1 : 0;
    cor += ((y > x) == lab) ? 1 : 0;  // argmax with first-index tie-break
}

// ---------------- kernel 1: per-row partials (deterministic) ----------------
__global__ __launch_bounds__(256) void pl_partials(
    const float* __restrict__ logits,   // [BATCH*BATCH*2]
    const int* __restrict__ tp,         // [BATCH]
    const int* __restrict__ tg,         // [BATCH]
    double* __restrict__ part_wnll,     // [BATCH]
    int* __restrict__ part_pos,         // [BATCH]
    int* __restrict__ part_cor)         // [BATCH]
{
    __shared__ int s_tg[BATCH];         // 16 KiB
    const int t = threadIdx.x;
    const int row = blockIdx.x;
    const float4* rowp =
        reinterpret_cast<const float4*>(logits) + (size_t)row * (BATCH / 2);

    // (1) issue first 4 row loads immediately — independent of LDS staging
    float4 q0 = rowp[t];
    float4 q1 = rowp[t + 256];
    float4 q2 = rowp[t + 512];
    float4 q3 = rowp[t + 768];

    // (2) stage gallery targets into LDS (int4-vectorized), then barrier
    {
        const int4* tg4 = reinterpret_cast<const int4*>(tg);
        int4* s4 = reinterpret_cast<int4*>(s_tg);
#pragma unroll
        for (int v = 0; v < 4; ++v) s4[t + v * 256] = tg4[t + v * 256];
    }
    const int my = tp[row];  // wave-uniform scalar load
    __syncthreads();

    // (3) issue next 4 row loads before computing on the first 4
    float4 q4 = rowp[t + 1024];
    float4 q5 = rowp[t + 1280];
    float4 q6 = rowp[t + 1536];
    float4 q7 = rowp[t + 2048 - 256];   // t + 1792

    float sum_all = 0.f;   // sum of nll over all pairs this thread sees
    float sum_pos = 0.f;   // sum of nll over positive pairs only
    int pos = 0, cor = 0;

#define PL_CHUNK(Q, K)                                                      \
    {                                                                        \
        const int2 g = *reinterpret_cast<const int2*>(&s_tg[2 * (t + (K)*256)]); \
        pl_pair((Q).x, (Q).y, my == g.x, sum_all, sum_pos, pos, cor);        \
        pl_pair((Q).z, (Q).w, my == g.y, sum_all, sum_pos, pos, cor);        \
    }
    PL_CHUNK(q0, 0) PL_CHUNK(q1, 1) PL_CHUNK(q2, 2) PL_CHUNK(q3, 3)
    PL_CHUNK(q4, 4) PL_CHUNK(q5, 5) PL_CHUNK(q6, 6) PL_CHUNK(q7, 7)
#undef PL_CHUNK

    // weighted combination, then wave64 shuffle reduce (double for the sum)
    double dw = (double)W_NEG_F * (double)sum_all +
                (1.0 - (double)W_NEG_F) * (double)sum_pos;
#pragma unroll
    for (int off = 32; off > 0; off >>= 1) {
        dw += __shfl_down(dw, off);
        pos += __shfl_down(pos, off);
        cor += __shfl_down(cor, off);
    }
    __shared__ double s_dw[4];
    __shared__ int s_pos[4], s_cor[4];
    const int wave = t >> 6, lane = t & 63;
    if (lane == 0) { s_dw[wave] = dw; s_pos[wave] = pos; s_cor[wave] = cor; }
    __syncthreads();
    if (t == 0) {
        part_wnll[row] = s_dw[0] + s_dw[1] + s_dw[2] + s_dw[3];
        part_pos[row] = s_pos[0] + s_pos[1] + s_pos[2] + s_pos[3];
        part_cor[row] = s_cor[0] + s_cor[1] + s_cor[2] + s_cor[3];
    }
}

// ---------------- kernel 2: fixed-order final reduce ----------------
__global__ __launch_bounds__(256) void pl_final(
    const double* __restrict__ part_wnll,
    const int* __restrict__ part_pos,
    const int* __restrict__ part_cor,
    float* __restrict__ out)            // out[0]=loss, out[1]=prec
{
    const int t = threadIdx.x;
    double dw = 0.0;
    long long pos = 0, cor = 0;
    for (int v = t; v < BATCH; v += 256) {
        dw += part_wnll[v];
        pos += (long long)part_pos[v];
        cor += (long long)part_cor[v];
    }
#pragma unroll
    for (int off = 32; off > 0; off >>= 1) {
        dw += __shfl_down(dw, off);
        pos += __shfl_down(pos, off);
        cor += __shfl_down(cor, off);
    }
    __shared__ double s_dw[4];
    __shared__ long long s_pos[4], s_cor[4];
    const int wave = t >> 6, lane = t & 63;
    if (lane == 0) { s_dw[wave] = dw; s_pos[wave] = pos; s_cor[wave] = cor; }
    __syncthreads();
    if (t == 0) {
        const double tot = s_dw[0] + s_dw[1] + s_dw[2] + s_dw[3];
        const long long P = s_pos[0] + s_pos[1] + s_pos[2] + s_pos[3];
        const long long C = s_cor[0] + s_cor[1] + s_cor[2] + s_cor[3];
        const double NP = (double)BATCH * (double)BATCH;
        // sum_w is exact given the positive count
        const double sum_w = (double)P + (NP - (double)P) * (double)W_NEG_F;
        out[0] = (float)(tot / sum_w);
        out[1] = (float)(100.0 * (double)C / NP);
    }
}

extern "C" void kernel_launch(void* const* d_in, const int* in_sizes, int n_in,
                              void* d_out, int out_size, void* d_ws, size_t ws_size,
                              hipStream_t stream) {
    const float* logits = (const float*)d_in[0];  // cls_encode [4096,4096,2] f32
    const int* tp = (const int*)d_in[1];          // tar_probe  [4096] i32
    const int* tg = (const int*)d_in[2];          // tar_gallery[4096] i32
    float* out = (float*)d_out;                   // [loss, prec]

    // workspace layout: 4096 doubles | 4096 ints | 4096 ints  (48 KiB)
    double* part_wnll = (double*)d_ws;
    int* part_pos = (int*)((char*)d_ws + BATCH * sizeof(double));
    int* part_cor = part_pos + BATCH;

    pl_partials<<<BATCH, 256, 0, stream>>>(logits, tp, tg, part_wnll, part_pos,
                                           part_cor);
    pl_final<<<1, 256, 0, stream>>>(part_wnll, part_pos, part_cor, out);
}

// Round 5
// 31.639 us; speedup vs baseline: 5.2034x; 1.0035x over previous
//
#include <hip/hip_runtime.h>

// PairwiseLoss: weighted 2-class cross-entropy + top-1 accuracy over all
// probe×gallery pairs.
//   labels[i,j] = (tp[i]==tg[j]); logits[i,j,:] = cls_encode[i,j,0:2]
//   loss = sum(w*nll)/sum(w),  w = label ? 1 : 1/4095
//   prec = 100 * mean(argmax(logits)==label)
//
// R1: libm softplus in predicated ternary -> VALU-bound (116 us, VALUBusy 100%).
// R2: __expf/__logf branch-free softplus -> 33 us.
// R3 FAILED: fused last-block ticket w/ __threadfence -> per-block L2
//     writebacks (non-coherent per-XCD L2) -> 250 us. Reverted.
// R4: 4 loads hoisted above staging barrier -> 31.7 us. Barely helped because
//     __syncthreads emits s_waitcnt vmcnt(0) -> the barrier DRAINS the
//     prefetch (m97 compiler behavior).
// R5: remove the barrier entirely. tg is 16 KB = L1/L2-resident; read it
//     directly as int2 (no LDS staging). Issue all 16 loads upfront with
//     named regs: 8x int2 (fast, cache-warm) then 8x float4 (HBM). Counted
//     vmcnt gives a 16-deep never-drained pipeline per wave.

constexpr int BATCH = 4096;
constexpr float W_NEG_F = 1.0f / 4095.0f;  // matches fp32 W_NEG in reference

__device__ __forceinline__ void pl_pair(float x, float y, bool lab,
                                        float& sum_all, float& sum_pos,
                                        int& pos, int& cor) {
    const float e = y - x;            // d when lab==0
    // softplus part log(1+exp(-|d|)) is label-independent since |d|=|e|
    const float t = __logf(1.f + __expf(-fabsf(e)));
    // max(d,0): d = lab ? -e : e  ->  lab ? max(-e,0) : max(e,0)
    const float m = lab ? fmaxf(-e, 0.f) : fmaxf(e, 0.f);
    const float nll = m + t;
    sum_all += nll;
    sum_pos += lab ? nll : 0.f;
    pos += lab ? 1 : 0;
    cor += ((y > x) == lab) ? 1 : 0;  // argmax with first-index tie-break
}

// ---------------- kernel 1: per-row partials (deterministic) ----------------
__global__ __launch_bounds__(256) void pl_partials(
    const float* __restrict__ logits,   // [BATCH*BATCH*2]
    const int* __restrict__ tp,         // [BATCH]
    const int* __restrict__ tg,         // [BATCH]
    double* __restrict__ part_wnll,     // [BATCH]
    int* __restrict__ part_pos,         // [BATCH]
    int* __restrict__ part_cor)         // [BATCH]
{
    const int t = threadIdx.x;
    const int row = blockIdx.x;
    const float4* rowp =
        reinterpret_cast<const float4*>(logits) + (size_t)row * (BATCH / 2);
    const int2* tg2 = reinterpret_cast<const int2*>(tg);

    // Issue ALL loads upfront, named registers, no barrier anywhere before
    // compute. Gallery int2s first (L1/L2-warm -> complete early in vmcnt
    // order), then the 8 HBM float4s.
    const int2 g0 = tg2[t];
    const int2 g1 = tg2[t + 256];
    const int2 g2 = tg2[t + 512];
    const int2 g3 = tg2[t + 768];
    const int2 g4 = tg2[t + 1024];
    const int2 g5 = tg2[t + 1280];
    const int2 g6 = tg2[t + 1536];
    const int2 g7 = tg2[t + 1792];
    const float4 q0 = rowp[t];
    const float4 q1 = rowp[t + 256];
    const float4 q2 = rowp[t + 512];
    const float4 q3 = rowp[t + 768];
    const float4 q4 = rowp[t + 1024];
    const float4 q5 = rowp[t + 1280];
    const float4 q6 = rowp[t + 1536];
    const float4 q7 = rowp[t + 1792];
    const int my = tp[row];  // wave-uniform -> scalar load

    float sum_all = 0.f;   // sum of nll over all pairs this thread sees
    float sum_pos = 0.f;   // sum of nll over positive pairs only
    int pos = 0, cor = 0;

#define PL_CHUNK(Q, G)                                                   \
    pl_pair((Q).x, (Q).y, my == (G).x, sum_all, sum_pos, pos, cor);      \
    pl_pair((Q).z, (Q).w, my == (G).y, sum_all, sum_pos, pos, cor);
    PL_CHUNK(q0, g0) PL_CHUNK(q1, g1) PL_CHUNK(q2, g2) PL_CHUNK(q3, g3)
    PL_CHUNK(q4, g4) PL_CHUNK(q5, g5) PL_CHUNK(q6, g6) PL_CHUNK(q7, g7)
#undef PL_CHUNK

    // weighted combination, then wave64 shuffle reduce (double for the sum)
    double dw = (double)W_NEG_F * (double)sum_all +
                (1.0 - (double)W_NEG_F) * (double)sum_pos;
#pragma unroll
    for (int off = 32; off > 0; off >>= 1) {
        dw += __shfl_down(dw, off);
        pos += __shfl_down(pos, off);
        cor += __shfl_down(cor, off);
    }
    __shared__ double s_dw[4];
    __shared__ int s_pos[4], s_cor[4];
    const int wave = t >> 6, lane = t & 63;
    if (lane == 0) { s_dw[wave] = dw; s_pos[wave] = pos; s_cor[wave] = cor; }
    __syncthreads();  // tail only — all loads already consumed, drain is free
    if (t == 0) {
        part_wnll[row] = s_dw[0] + s_dw[1] + s_dw[2] + s_dw[3];
        part_pos[row] = s_pos[0] + s_pos[1] + s_pos[2] + s_pos[3];
        part_cor[row] = s_cor[0] + s_cor[1] + s_cor[2] + s_cor[3];
    }
}

// ---------------- kernel 2: fixed-order final reduce ----------------
__global__ __launch_bounds__(256) void pl_final(
    const double* __restrict__ part_wnll,
    const int* __restrict__ part_pos,
    const int* __restrict__ part_cor,
    float* __restrict__ out)            // out[0]=loss, out[1]=prec
{
    const int t = threadIdx.x;
    double dw = 0.0;
    long long pos = 0, cor = 0;
    for (int v = t; v < BATCH; v += 256) {
        dw += part_wnll[v];
        pos += (long long)part_pos[v];
        cor += (long long)part_cor[v];
    }
#pragma unroll
    for (int off = 32; off > 0; off >>= 1) {
        dw += __shfl_down(dw, off);
        pos += __shfl_down(pos, off);
        cor += __shfl_down(cor, off);
    }
    __shared__ double s_dw[4];
    __shared__ long long s_pos[4], s_cor[4];
    const int wave = t >> 6, lane = t & 63;
    if (lane == 0) { s_dw[wave] = dw; s_pos[wave] = pos; s_cor[wave] = cor; }
    __syncthreads();
    if (t == 0) {
        const double tot = s_dw[0] + s_dw[1] + s_dw[2] + s_dw[3];
        const long long P = s_pos[0] + s_pos[1] + s_pos[2] + s_pos[3];
        const long long C = s_cor[0] + s_cor[1] + s_cor[2] + s_cor[3];
        const double NP = (double)BATCH * (double)BATCH;
        // sum_w is exact given the positive count
        const double sum_w = (double)P + (NP - (double)P) * (double)W_NEG_F;
        out[0] = (float)(tot / sum_w);
        out[1] = (float)(100.0 * (double)C / NP);
    }
}

extern "C" void kernel_launch(void* const* d_in, const int* in_sizes, int n_in,
                              void* d_out, int out_size, void* d_ws, size_t ws_size,
                              hipStream_t stream) {
    const float* logits = (const float*)d_in[0];  // cls_encode [4096,4096,2] f32
    const int* tp = (const int*)d_in[1];          // tar_probe  [4096] i32
    const int* tg = (const int*)d_in[2];          // tar_gallery[4096] i32
    float* out = (float*)d_out;                   // [loss, prec]

    // workspace layout: 4096 doubles | 4096 ints | 4096 ints  (48 KiB)
    double* part_wnll = (double*)d_ws;
    int* part_pos = (int*)((char*)d_ws + BATCH * sizeof(double));
    int* part_cor = part_pos + BATCH;

    pl_partials<<<BATCH, 256, 0, stream>>>(logits, tp, tg, part_wnll, part_pos,
                                           part_cor);
    pl_final<<<1, 256, 0, stream>>>(part_wnll, part_pos, part_cor, out);
}

// Round 6
// 30.259 us; speedup vs baseline: 5.4407x; 1.0456x over previous
//
#include <hip/hip_runtime.h>

// PairwiseLoss: weighted 2-class cross-entropy + top-1 accuracy over all
// probe×gallery pairs.
//   labels[i,j] = (tp[i]==tg[j]); logits[i,j,:] = cls_encode[i,j,0:2]
//   loss = sum(w*nll)/sum(w),  w = label ? 1 : 1/4095
//   prec = 100 * mean(argmax(logits)==label)
//
// R1: libm softplus, predicated -> VALU-bound, 116 us.
// R2: __expf/__logf branch-free softplus -> 33 us.
// R3 FAILED: fused last-block ticket w/ __threadfence -> per-block L2
//     writebacks (non-coherent per-XCD L2) -> 250 us. Reverted.
// R4: hoisted loads above barrier -> 31.7 us (barrier drains vmcnt).
// R5: no barrier, 16-deep upfront loads -> 31.6 us (NEUTRAL -> not
//     pipeline-structure-limited).
// R6: 2 rows per block (2048 blocks): halves tail-reduce count, halves
//     redundant tg L2 traffic, doubles load:tail ratio. Discriminates
//     block-overhead slack vs HBM-stream floor.

constexpr int BATCH = 4096;
constexpr int NPART = BATCH / 2;           // 2048 blocks, 2 rows each
constexpr float W_NEG_F = 1.0f / 4095.0f;  // matches fp32 W_NEG in reference

__device__ __forceinline__ void pl_pair(float x, float y, bool lab,
                                        float& sum_all, float& sum_pos,
                                        int& pos, int& cor) {
    const float e = y - x;            // d when lab==0
    // log(1+exp(-|d|)) is label-independent since |d|=|e|
    const float t = __logf(1.f + __expf(-fabsf(e)));
    const float m = lab ? fmaxf(-e, 0.f) : fmaxf(e, 0.f);  // max(d,0)
    const float nll = m + t;
    sum_all += nll;
    sum_pos += lab ? nll : 0.f;
    pos += lab ? 1 : 0;
    cor += ((y > x) == lab) ? 1 : 0;  // argmax with first-index tie-break
}

// ---------------- kernel 1: per-2-row partials (deterministic) --------------
__global__ __launch_bounds__(256) void pl_partials(
    const float* __restrict__ logits,   // [BATCH*BATCH*2]
    const int* __restrict__ tp,         // [BATCH]
    const int* __restrict__ tg,         // [BATCH]
    double* __restrict__ part_wnll,     // [NPART]
    int* __restrict__ part_pos,         // [NPART]
    int* __restrict__ part_cor)         // [NPART]
{
    const int t = threadIdx.x;
    const int row0 = 2 * blockIdx.x;
    const float4* rowpA =
        reinterpret_cast<const float4*>(logits) + (size_t)row0 * (BATCH / 2);
    const float4* rowpB = rowpA + (BATCH / 2);
    const int2* tg2 = reinterpret_cast<const int2*>(tg);

    // Issue ALL loads upfront with named registers; no barrier before compute.
    // Gallery int2s first (L2-warm), then 16 HBM float4s (2 rows).
    const int2 g0 = tg2[t];
    const int2 g1 = tg2[t + 256];
    const int2 g2 = tg2[t + 512];
    const int2 g3 = tg2[t + 768];
    const int2 g4 = tg2[t + 1024];
    const int2 g5 = tg2[t + 1280];
    const int2 g6 = tg2[t + 1536];
    const int2 g7 = tg2[t + 1792];
    const float4 a0 = rowpA[t];
    const float4 a1 = rowpA[t + 256];
    const float4 a2 = rowpA[t + 512];
    const float4 a3 = rowpA[t + 768];
    const float4 a4 = rowpA[t + 1024];
    const float4 a5 = rowpA[t + 1280];
    const float4 a6 = rowpA[t + 1536];
    const float4 a7 = rowpA[t + 1792];
    const float4 b0 = rowpB[t];
    const float4 b1 = rowpB[t + 256];
    const float4 b2 = rowpB[t + 512];
    const float4 b3 = rowpB[t + 768];
    const float4 b4 = rowpB[t + 1024];
    const float4 b5 = rowpB[t + 1280];
    const float4 b6 = rowpB[t + 1536];
    const float4 b7 = rowpB[t + 1792];
    const int my0 = tp[row0];      // wave-uniform -> scalar loads
    const int my1 = tp[row0 + 1];

    float sum_all = 0.f;   // nll over all pairs this thread sees (both rows)
    float sum_pos = 0.f;   // nll over positive pairs only
    int pos = 0, cor = 0;

#define PL_CHUNK(Q, G, MY)                                               \
    pl_pair((Q).x, (Q).y, (MY) == (G).x, sum_all, sum_pos, pos, cor);    \
    pl_pair((Q).z, (Q).w, (MY) == (G).y, sum_all, sum_pos, pos, cor);
    PL_CHUNK(a0, g0, my0) PL_CHUNK(a1, g1, my0) PL_CHUNK(a2, g2, my0)
    PL_CHUNK(a3, g3, my0) PL_CHUNK(a4, g4, my0) PL_CHUNK(a5, g5, my0)
    PL_CHUNK(a6, g6, my0) PL_CHUNK(a7, g7, my0)
    PL_CHUNK(b0, g0, my1) PL_CHUNK(b1, g1, my1) PL_CHUNK(b2, g2, my1)
    PL_CHUNK(b3, g3, my1) PL_CHUNK(b4, g4, my1) PL_CHUNK(b5, g5, my1)
    PL_CHUNK(b6, g6, my1) PL_CHUNK(b7, g7, my1)
#undef PL_CHUNK

    // weighted combination, then wave64 shuffle reduce (double for the sum)
    double dw = (double)W_NEG_F * (double)sum_all +
                (1.0 - (double)W_NEG_F) * (double)sum_pos;
#pragma unroll
    for (int off = 32; off > 0; off >>= 1) {
        dw += __shfl_down(dw, off);
        pos += __shfl_down(pos, off);
        cor += __shfl_down(cor, off);
    }
    __shared__ double s_dw[4];
    __shared__ int s_pos[4], s_cor[4];
    const int wave = t >> 6, lane = t & 63;
    if (lane == 0) { s_dw[wave] = dw; s_pos[wave] = pos; s_cor[wave] = cor; }
    __syncthreads();  // tail only — all loads already consumed
    if (t == 0) {
        part_wnll[blockIdx.x] = s_dw[0] + s_dw[1] + s_dw[2] + s_dw[3];
        part_pos[blockIdx.x] = s_pos[0] + s_pos[1] + s_pos[2] + s_pos[3];
        part_cor[blockIdx.x] = s_cor[0] + s_cor[1] + s_cor[2] + s_cor[3];
    }
}

// ---------------- kernel 2: fixed-order final reduce ----------------
__global__ __launch_bounds__(256) void pl_final(
    const double* __restrict__ part_wnll,
    const int* __restrict__ part_pos,
    const int* __restrict__ part_cor,
    float* __restrict__ out)            // out[0]=loss, out[1]=prec
{
    const int t = threadIdx.x;
    double dw = 0.0;
    long long pos = 0, cor = 0;
    for (int v = t; v < NPART; v += 256) {
        dw += part_wnll[v];
        pos += (long long)part_pos[v];
        cor += (long long)part_cor[v];
    }
#pragma unroll
    for (int off = 32; off > 0; off >>= 1) {
        dw += __shfl_down(dw, off);
        pos += __shfl_down(pos, off);
        cor += __shfl_down(cor, off);
    }
    __shared__ double s_dw[4];
    __shared__ long long s_pos[4], s_cor[4];
    const int wave = t >> 6, lane = t & 63;
    if (lane == 0) { s_dw[wave] = dw; s_pos[wave] = pos; s_cor[wave] = cor; }
    __syncthreads();
    if (t == 0) {
        const double tot = s_dw[0] + s_dw[1] + s_dw[2] + s_dw[3];
        const long long P = s_pos[0] + s_pos[1] + s_pos[2] + s_pos[3];
        const long long C = s_cor[0] + s_cor[1] + s_cor[2] + s_cor[3];
        const double NP = (double)BATCH * (double)BATCH;
        // sum_w is exact given the positive count
        const double sum_w = (double)P + (NP - (double)P) * (double)W_NEG_F;
        out[0] = (float)(tot / sum_w);
        out[1] = (float)(100.0 * (double)C / NP);
    }
}

extern "C" void kernel_launch(void* const* d_in, const int* in_sizes, int n_in,
                              void* d_out, int out_size, void* d_ws, size_t ws_size,
                              hipStream_t stream) {
    const float* logits = (const float*)d_in[0];  // cls_encode [4096,4096,2] f32
    const int* tp = (const int*)d_in[1];          // tar_probe  [4096] i32
    const int* tg = (const int*)d_in[2];          // tar_gallery[4096] i32
    float* out = (float*)d_out;                   // [loss, prec]

    // workspace layout: 2048 doubles | 2048 ints | 2048 ints  (24 KiB)
    double* part_wnll = (double*)d_ws;
    int* part_pos = (int*)((char*)d_ws + NPART * sizeof(double));
    int* part_cor = part_pos + NPART;

    pl_partials<<<NPART, 256, 0, stream>>>(logits, tp, tg, part_wnll, part_pos,
                                           part_cor);
    pl_final<<<1, 256, 0, stream>>>(part_wnll, part_pos, part_cor, out);
}